// Round 6
// baseline (130.709 us; speedup 1.0000x reference)
//
#include <hip/hip_runtime.h>

// Problem constants
#define BATCH 64
#define GH 14
#define GW 14
#define NPATCH (GH*GW)        // 196
#define M_ROWS (BATCH*NPATCH) // 12544
#define KDIM 768              // 3*16*16
#define DDIM 384              // EMBED
#define HW (224*224)

typedef __attribute__((ext_vector_type(8))) short s16x8;
typedef __attribute__((ext_vector_type(4))) float f32x4;
typedef __attribute__((ext_vector_type(4))) unsigned short u16x4;

__device__ __forceinline__ unsigned short f2bf(float f) {
    unsigned int u = __float_as_uint(f);
    u += 0x7fff + ((u >> 16) & 1);   // round-to-nearest-even
    return (unsigned short)(u >> 16);
}

__device__ __forceinline__ s16x8 cvt8(float4 lo, float4 hi) {
    s16x8 o;
    o[0] = (short)f2bf(lo.x); o[1] = (short)f2bf(lo.y);
    o[2] = (short)f2bf(lo.z); o[3] = (short)f2bf(lo.w);
    o[4] = (short)f2bf(hi.x); o[5] = (short)f2bf(hi.y);
    o[6] = (short)f2bf(hi.z); o[7] = (short)f2bf(hi.w);
    return o;
}

// ---------------- kernel 1: weight fp32 -> bf16 cast (B^T, row-major 384x768) --
__global__ __launch_bounds__(256) void wcast_kernel(const float* __restrict__ w,
                                                    unsigned short* __restrict__ W) {
    int t = blockIdx.x * 256 + threadIdx.x;   // 73728 float4s total
    float4 v = ((const float4*)w)[t];
    u16x4 o = { f2bf(v.x), f2bf(v.y), f2bf(v.z), f2bf(v.w) };
    *(u16x4*)(W + t * 4) = o;
}

// ---------------- kernel 2: fused im2col + entropy + GEMM + bias + LayerNorm --
// 392 blocks x 384 threads (6 waves), 32 rows/block, full N=384 (LN needs it).
// ROUND-6 STRUCTURE: the whole A panel (32 rows x K=768 bf16 = 48 KB) is
// staged into LDS ONCE (it's L2-warm after the entropy pass), then the K-loop
// runs with ZERO barriers: each wave free-runs all 12 K-tiles, streaming its
// wave-private B column-slice global(L2)->reg and reading A frags from the
// read-only LDS panel. No lockstep, no vmcnt(0) drains -- latency hidden by
// TLP (3 blocks/CU via ~50 KB LDS) + per-iter ILP (8 B loads issued first).
// A swizzle per 64-K tile unchanged: write slot (ksg^(row&7)), read slot
// sw=(ks*4+quad)^(cl&7). #pragma unroll 1 on K-loop: VGPR stays ~100 (TLP
// beats ILP here; register pressure killed rounds 3/4).
__global__ __launch_bounds__(384) void fused_kernel(const float* __restrict__ img,
                                                    const unsigned short* __restrict__ Bt,
                                                    const float* __restrict__ bias,
                                                    const float* __restrict__ gamma,
                                                    const float* __restrict__ beta,
                                                    float* __restrict__ C,
                                                    float* __restrict__ ent) {
    __shared__ __align__(16) unsigned short As[12 * 32 * 64];  // 48 KB: full A panel
    __shared__ int hist[6][32];
    __shared__ float sred[32], sred2[32], smean[32], srstd[32];

    const int tid  = threadIdx.x;
    const int lane = tid & 63;
    const int wv   = tid >> 6;                // wave 0..5
    const int quad = lane >> 4;
    const int cl   = lane & 15;
    const int rowBase = blockIdx.x * 32;

    if (tid < 32) { sred[tid] = 0.0f; sred2[tid] = 0.0f; }

    // ---- A-staging constants (threads 0..255 own one 16B chunk per K-tile) ----
    // chunk: row r1=tid>>3 (0..31), K-subchunk ksg=tid&7. For tile t:
    // channel=(t>>2), pixel-row block=(t&3)*4+(ksg>>1), col=(ksg&1)*8.
    const int r1  = tid >> 3, ksg = tid & 7;
    const int sA1 = r1 * 64 + (ksg ^ (r1 & 7)) * 8;
    const float* pA1;
    {
        int p = rowBase + r1, b = p / NPATCH, n = p - b * NPATCH;
        int ph = n / GW, pw_ = n - ph * GW;
        pA1 = img + (size_t)b * (3 * HW) + (ph * 16 + (ksg >> 1)) * 224 + pw_ * 16 + (ksg & 1) * 8;
    }
    // ---- B direct-read base: wave wv owns output cols [wv*64, wv*64+64).
    // frag(j,ks,t) = 8 shorts at pBr + j*16*KDIM + t*64 + ks*32.
    const unsigned short* pBr = Bt + (size_t)(wv * 64 + cl) * KDIM + quad * 8;

    // ---- phase 1: patch entropy (wave-per-patch, 1-deep pixel prefetch).
    // Doubles as the L2 warm-up for the A panel pixels. ----
    {
        const int pr  = lane >> 2;            // pixel row 0..15
        const int cc4 = (lane & 3) * 4;       // pixel col 0,4,8,12
        int p0 = rowBase + wv, b0 = p0 / NPATCH, n0i = p0 - b0 * NPATCH;
        int ph0 = n0i / GW, pw0 = n0i - ph0 * GW;
        const float* bp = img + (size_t)b0 * (3 * HW) + (ph0 * 16 + pr) * 224 + pw0 * 16 + cc4;
        float4 c0 = *(const float4*)(bp);
        float4 c1 = *(const float4*)(bp + HW);
        float4 c2 = *(const float4*)(bp + 2 * HW);
        for (int pp = wv; pp < 32; pp += 6) {
            float4 n0, n1, n2;
            if (pp + 6 < 32) {
                int p = rowBase + pp + 6, b = p / NPATCH, n = p - b * NPATCH;
                int ph = n / GW, pw_ = n - ph * GW;
                const float* np = img + (size_t)b * (3 * HW) + (ph * 16 + pr) * 224 + pw_ * 16 + cc4;
                n0 = *(const float4*)(np);
                n1 = *(const float4*)(np + HW);
                n2 = *(const float4*)(np + 2 * HW);
            }
            if (lane < 32) hist[wv][lane] = 0;
            asm volatile("s_waitcnt lgkmcnt(0)" ::: "memory");   // zero visible wave-wide
            float g[4] = { (c0.x + c1.x + c2.x) / 3.0f, (c0.y + c1.y + c2.y) / 3.0f,
                           (c0.z + c1.z + c2.z) / 3.0f, (c0.w + c1.w + c2.w) / 3.0f };
#pragma unroll
            for (int j = 0; j < 4; ++j) {
                int bin = (int)(g[j] * 31.0f);
                bin = bin < 0 ? 0 : (bin > 31 ? 31 : bin);
                atomicAdd(&hist[wv][bin], 1);
            }
            asm volatile("s_waitcnt lgkmcnt(0)" ::: "memory");   // atomics done
            float t = 0.0f;
            if (lane < 32) {
                float prb = (float)hist[wv][lane] * (1.0f / 256.0f);
                t = -prb * log2f(prb + 1e-10f);
            }
#pragma unroll
            for (int off = 32; off; off >>= 1) t += __shfl_xor(t, off);
            if (lane == 0) ent[rowBase + pp] = t * (1.0f / 5.0f);  // / log2(32)
            c0 = n0; c1 = n1; c2 = n2;
        }
    }

    // ---- phase 2: stage the whole A panel (L2-warm), ONE barrier ----
    if (tid < 256) {
#pragma unroll 4
        for (int t = 0; t < 12; ++t) {
            const float* p = pA1 + (t >> 2) * HW + (t & 3) * (4 * 224);
            float4 lo = *(const float4*)(p);
            float4 hi = *(const float4*)(p + 4);
            *(s16x8*)(As + t * 2048 + sA1) = cvt8(lo, hi);
        }
    }
    __syncthreads();                          // the ONLY pre-epilogue barrier

    // ---- phase 3: barrier-free K-loop, wave free-runs all 12 tiles ----
    f32x4 acc[2][4] = {};
#pragma unroll 1
    for (int t = 0; t < 12; ++t) {
        const unsigned short* At = As + t * 2048;
        s16x8 bf[2][4];
#pragma unroll
        for (int ks = 0; ks < 2; ++ks)
#pragma unroll
            for (int j = 0; j < 4; ++j)
                bf[ks][j] = *(const s16x8*)(pBr + j * (16 * KDIM) + t * 64 + ks * 32);
#pragma unroll
        for (int ks = 0; ks < 2; ++ks) {
            const int sw = (ks * 4 + quad) ^ (cl & 7);
            s16x8 af0 = *(const s16x8*)(At + (0 * 16 + cl) * 64 + sw * 8);
            s16x8 af1 = *(const s16x8*)(At + (1 * 16 + cl) * 64 + sw * 8);
#pragma unroll
            for (int j = 0; j < 4; ++j) {
                acc[0][j] = __builtin_amdgcn_mfma_f32_16x16x32_bf16(af0, bf[ks][j], acc[0][j], 0, 0, 0);
                acc[1][j] = __builtin_amdgcn_mfma_f32_16x16x32_bf16(af1, bf[ks][j], acc[1][j], 0, 0, 0);
            }
        }
    }

    // ---- epilogue: bias + LayerNorm(384) + write ----
    float bv[4], gv[4], btv[4];
#pragma unroll
    for (int j = 0; j < 4; ++j) {
        int col = wv * 64 + j * 16 + cl;
        bv[j] = bias[col]; gv[j] = gamma[col]; btv[j] = beta[col];
    }

#pragma unroll
    for (int i = 0; i < 2; ++i) {
#pragma unroll
        for (int r = 0; r < 4; ++r) {
            float s1 = 0.0f, s2 = 0.0f;
#pragma unroll
            for (int j = 0; j < 4; ++j) {
                float v = acc[i][j][r] + bv[j];
                s1 += v; s2 += v * v;
            }
#pragma unroll
            for (int off = 1; off < 16; off <<= 1) {
                s1 += __shfl_xor(s1, off);
                s2 += __shfl_xor(s2, off);
            }
            if (cl == 0) {
                int row = i * 16 + quad * 4 + r;
                atomicAdd(&sred[row], s1);
                atomicAdd(&sred2[row], s2);
            }
        }
    }
    __syncthreads();
    if (tid < 32) {
        float mu  = sred[tid] * (1.0f / (float)DDIM);
        float var = sred2[tid] * (1.0f / (float)DDIM) - mu * mu;
        smean[tid] = mu;
        srstd[tid] = rsqrtf(var + 1e-5f);
    }
    __syncthreads();

#pragma unroll
    for (int i = 0; i < 2; ++i) {
#pragma unroll
        for (int r = 0; r < 4; ++r) {
            int row = i * 16 + quad * 4 + r;
            float mu = smean[row], rs = srstd[row];
            float* crow = C + (size_t)(rowBase + row) * DDIM;
#pragma unroll
            for (int j = 0; j < 4; ++j)
                crow[wv * 64 + j * 16 + cl] = (acc[i][j][r] + bv[j] - mu) * rs * gv[j] + btv[j];
        }
    }
}

extern "C" void kernel_launch(void* const* d_in, const int* in_sizes, int n_in,
                              void* d_out, int out_size, void* d_ws, size_t ws_size,
                              hipStream_t stream) {
    const float* img = (const float*)d_in[0];
    const float* pw  = (const float*)d_in[1];
    const float* pb  = (const float*)d_in[2];
    const float* gam = (const float*)d_in[3];
    const float* bet = (const float*)d_in[4];
    float* out = (float*)d_out;

    unsigned short* Wbf = (unsigned short*)d_ws;          // 384*768*2 = 589824 B
    float* ent = out + (size_t)M_ROWS * DDIM;             // entropy after x

    hipLaunchKernelGGL(wcast_kernel, dim3(288), dim3(256), 0, stream, pw, Wbf);
    hipLaunchKernelGGL(fused_kernel, dim3(392), dim3(384), 0, stream,
                       img, Wbf, pb, gam, bet, out, ent);
}

// Round 7
// 116.946 us; speedup vs baseline: 1.1177x; 1.1177x over previous
//
#include <hip/hip_runtime.h>

// Problem constants
#define BATCH 64
#define GH 14
#define GW 14
#define NPATCH (GH*GW)        // 196
#define M_ROWS (BATCH*NPATCH) // 12544
#define KDIM 768              // 3*16*16
#define DDIM 384              // EMBED
#define HW (224*224)

typedef __attribute__((ext_vector_type(8))) short s16x8;
typedef __attribute__((ext_vector_type(4))) float f32x4;
typedef __attribute__((ext_vector_type(4))) unsigned short u16x4;

__device__ __forceinline__ unsigned short f2bf(float f) {
    unsigned int u = __float_as_uint(f);
    u += 0x7fff + ((u >> 16) & 1);   // round-to-nearest-even
    return (unsigned short)(u >> 16);
}

__device__ __forceinline__ void load_lds16(const void* g, void* l) {
    __builtin_amdgcn_global_load_lds(
        (const __attribute__((address_space(1))) unsigned int*)g,
        (__attribute__((address_space(3))) unsigned int*)l, 16, 0, 0);
}

// ------- kernel 1: fused im2col(bf16) + patch entropy + weight cast ----------
// (R0's proven kernel, verbatim.)
// blocks [0,3136): one wave per patch -> bf16 A row + grayscale histogram.
// blocks [3136,3424): weight fp32->bf16 cast (384x768 row-major = B^T).
__global__ __launch_bounds__(256) void patch_kernel(const float* __restrict__ img,
                                                    const float* __restrict__ w,
                                                    unsigned short* __restrict__ A,
                                                    unsigned short* __restrict__ W,
                                                    float* __restrict__ ent) {
    if (blockIdx.x >= 3136) {                 // ---- weight cast part ----
        int t = (blockIdx.x - 3136) * 256 + threadIdx.x;   // 73728 float4s
        float4 v = ((const float4*)w)[t];
        u16x4 o = { f2bf(v.x), f2bf(v.y), f2bf(v.z), f2bf(v.w) };
        *(u16x4*)(W + t * 4) = o;
        return;
    }
    __shared__ int hist[4][32];
    const int lane = threadIdx.x & 63;
    const int wave = threadIdx.x >> 6;
    const int p = blockIdx.x * 4 + wave;      // 0..12543 == A row index
    const int b = p / NPATCH;
    const int n = p - b * NPATCH;
    const int ph = n / GW, pw = n - ph * GW;

    if (lane < 32) hist[wave][lane] = 0;
    __syncthreads();

    const int r = lane >> 2;                  // pixel row in patch 0..15
    const int cc = (lane & 3) * 4;            // pixel col 0,4,8,12
    const float* base = img + (size_t)b * (3 * HW) + (ph * 16 + r) * 224 + pw * 16 + cc;

    float4 v0 = *(const float4*)(base);
    float4 v1 = *(const float4*)(base + HW);
    float4 v2 = *(const float4*)(base + 2 * HW);

    unsigned short* arow = A + (size_t)p * KDIM;
    u16x4 o0 = { f2bf(v0.x), f2bf(v0.y), f2bf(v0.z), f2bf(v0.w) };
    u16x4 o1 = { f2bf(v1.x), f2bf(v1.y), f2bf(v1.z), f2bf(v1.w) };
    u16x4 o2 = { f2bf(v2.x), f2bf(v2.y), f2bf(v2.z), f2bf(v2.w) };
    *(u16x4*)(arow + 0 * 256 + lane * 4) = o0;
    *(u16x4*)(arow + 1 * 256 + lane * 4) = o1;
    *(u16x4*)(arow + 2 * 256 + lane * 4) = o2;

    float g[4] = { (v0.x + v1.x + v2.x) / 3.0f,
                   (v0.y + v1.y + v2.y) / 3.0f,
                   (v0.z + v1.z + v2.z) / 3.0f,
                   (v0.w + v1.w + v2.w) / 3.0f };
#pragma unroll
    for (int j = 0; j < 4; ++j) {
        int bin = (int)(g[j] * 31.0f);
        bin = bin < 0 ? 0 : (bin > 31 ? 31 : bin);
        atomicAdd(&hist[wave][bin], 1);
    }
    __syncthreads();

    float t = 0.0f;
    if (lane < 32) {
        float pr = (float)hist[wave][lane] * (1.0f / 256.0f);
        t = -pr * log2f(pr + 1e-10f);
    }
#pragma unroll
    for (int off = 32; off; off >>= 1) t += __shfl_xor(t, off);
    if (lane == 0) ent[p] = t * (1.0f / 5.0f);   // / log2(32)
}

// ------- kernel 2: pure bf16 MFMA GEMM, 32x128 tiles, high occupancy ---------
// 1176 blocks (392 M-tiles x 3 N-tiles) x 256 threads (4 waves).
// LDS: double-buffered [As 4KB | Bs 16KB] = 40KB -> 4 blocks/CU, 16 waves/CU.
// Staging via global_load_lds(16B): 1280 chunks/tile, 5 per thread, linear LDS
// dst; XOR swizzle is pre-applied on the GLOBAL source (slot kss holds chunk
// kss^(row&7)); fragment read slot sw=(ks*4+quad)^(cl&7). ONE barrier/K-tile
// (stage next into buf^1 while computing buf). Writes raw x+bias to out;
// LayerNorm is a separate pass.
__global__ __launch_bounds__(256) void gemm_kernel(const unsigned short* __restrict__ A,
                                                   const unsigned short* __restrict__ Bt,
                                                   const float* __restrict__ bias,
                                                   float* __restrict__ C) {
    __shared__ __align__(16) unsigned short SH[2][1280 * 8];  // 40 KB

    const int tid  = threadIdx.x;
    const int lane = tid & 63;
    const int wv   = tid >> 6;                // wave 0..3
    const int quad = lane >> 4;
    const int cl   = lane & 15;
    const int rowBase = (blockIdx.x / 3) * 32;
    const int colBase = (blockIdx.x % 3) * 128;

    // ---- staging constants: 5 chunks per thread (c = i*256 + tid) ----
    // c <  256 : As chunk -> row r=c>>3, slot kss=c&7, src col chunk kss^(r&7)
    // c >= 256 : Bs chunk -> row n=(c-256)>>3, same swizzle
    const unsigned short* srcs[5];
    {
#pragma unroll
        for (int i = 0; i < 5; ++i) {
            int c = i * 256 + tid;
            if (c < 256) {
                int r = c >> 3, kss = c & 7, ksg = kss ^ (r & 7);
                srcs[i] = A + (size_t)(rowBase + r) * KDIM + ksg * 8;
            } else {
                int cc = c - 256;
                int n = cc >> 3, kss = cc & 7, ksg = kss ^ (n & 7);
                srcs[i] = Bt + (size_t)(colBase + n) * KDIM + ksg * 8;
            }
        }
    }
    const int dstOff = tid * 8;               // shorts; chunk c at (c*8)

    // ---- prologue: stage tile 0 into buf 0 ----
#pragma unroll
    for (int i = 0; i < 5; ++i)
        load_lds16(srcs[i], &SH[0][i * 2048 + dstOff]);
    __syncthreads();

    f32x4 acc[2][2] = {};
#pragma unroll
    for (int kt = 0; kt < 12; ++kt) {
        const int cur = kt & 1;
        if (kt < 11) {                        // stage tile kt+1 into other buf
#pragma unroll
            for (int i = 0; i < 5; ++i)
                load_lds16(srcs[i] + (kt + 1) * 64, &SH[cur ^ 1][i * 2048 + dstOff]);
        }
        const unsigned short* As = SH[cur];
        const unsigned short* Bs = SH[cur] + 2048;
#pragma unroll
        for (int ks = 0; ks < 2; ++ks) {
            const int sw = (ks * 4 + quad) ^ (cl & 7);
            s16x8 af[2], bf[2];
#pragma unroll
            for (int i = 0; i < 2; ++i)
                af[i] = *(const s16x8*)(As + ((i * 16 + cl) * 8 + sw) * 8);
#pragma unroll
            for (int j = 0; j < 2; ++j)
                bf[j] = *(const s16x8*)(Bs + ((wv * 32 + j * 16 + cl) * 8 + sw) * 8);
#pragma unroll
            for (int i = 0; i < 2; ++i)
#pragma unroll
                for (int j = 0; j < 2; ++j)
                    acc[i][j] = __builtin_amdgcn_mfma_f32_16x16x32_bf16(
                        af[i], bf[j], acc[i][j], 0, 0, 0);
        }
        __syncthreads();                      // staging done + reads done
    }

    // ---- epilogue: + bias, write raw x (LN is a separate pass) ----
    float bv[2];
#pragma unroll
    for (int j = 0; j < 2; ++j)
        bv[j] = bias[colBase + wv * 32 + j * 16 + cl];
#pragma unroll
    for (int i = 0; i < 2; ++i)
#pragma unroll
        for (int r = 0; r < 4; ++r) {
            int row = rowBase + i * 16 + quad * 4 + r;
            float* crow = C + (size_t)row * DDIM + colBase + wv * 32;
#pragma unroll
            for (int j = 0; j < 2; ++j)
                crow[j * 16 + cl] = acc[i][j][r] + bv[j];
        }
}

// ------- kernel 3: in-place LayerNorm(384) over rows of out -----------------
// 3136 blocks x 256 threads; wave wv handles row blockIdx*4+wv.
// Row = 192 float2; lane covers {lane, lane+64, lane+128} -> coalesced.
__global__ __launch_bounds__(256) void ln_kernel(float* __restrict__ x,
                                                 const float* __restrict__ gamma,
                                                 const float* __restrict__ beta) {
    const int lane = threadIdx.x & 63;
    const int wv   = threadIdx.x >> 6;
    const int row  = blockIdx.x * 4 + wv;

    float2* px = (float2*)(x + (size_t)row * DDIM);
    float2 v[3];
    float s1 = 0.0f, s2 = 0.0f;
#pragma unroll
    for (int k = 0; k < 3; ++k) {
        v[k] = px[lane + k * 64];
        s1 += v[k].x + v[k].y;
        s2 += v[k].x * v[k].x + v[k].y * v[k].y;
    }
#pragma unroll
    for (int off = 1; off < 64; off <<= 1) {
        s1 += __shfl_xor(s1, off);
        s2 += __shfl_xor(s2, off);
    }
    float mu  = s1 * (1.0f / (float)DDIM);
    float var = s2 * (1.0f / (float)DDIM) - mu * mu;
    float rs  = rsqrtf(var + 1e-5f);
#pragma unroll
    for (int k = 0; k < 3; ++k) {
        int c2 = lane + k * 64;
        float2 g = ((const float2*)gamma)[c2];
        float2 b = ((const float2*)beta)[c2];
        float2 o;
        o.x = (v[k].x - mu) * rs * g.x + b.x;
        o.y = (v[k].y - mu) * rs * g.y + b.y;
        px[c2] = o;
    }
}

extern "C" void kernel_launch(void* const* d_in, const int* in_sizes, int n_in,
                              void* d_out, int out_size, void* d_ws, size_t ws_size,
                              hipStream_t stream) {
    const float* img = (const float*)d_in[0];
    const float* pw  = (const float*)d_in[1];
    const float* pb  = (const float*)d_in[2];
    const float* gam = (const float*)d_in[3];
    const float* bet = (const float*)d_in[4];
    float* out = (float*)d_out;

    unsigned short* Abf = (unsigned short*)d_ws;                       // 12544*768*2 = 19267584 B
    unsigned short* Wbf = (unsigned short*)((char*)d_ws + 19267584);   // 384*768*2  = 589824 B
    float* ent = out + (size_t)M_ROWS * DDIM;                          // entropy after x

    hipLaunchKernelGGL(patch_kernel, dim3(3424), dim3(256), 0, stream,
                       img, pw, Abf, Wbf, ent);
    hipLaunchKernelGGL(gemm_kernel,  dim3(1176), dim3(256), 0, stream,
                       Abf, Wbf, pb, out);
    hipLaunchKernelGGL(ln_kernel,    dim3(3136), dim3(256), 0, stream,
                       out, gam, bet);
}

// Round 8
// 116.681 us; speedup vs baseline: 1.1202x; 1.0023x over previous
//
#include <hip/hip_runtime.h>

// Problem constants
#define BATCH 64
#define GH 14
#define GW 14
#define NPATCH (GH*GW)        // 196
#define M_ROWS (BATCH*NPATCH) // 12544
#define KDIM 768              // 3*16*16
#define DDIM 384              // EMBED
#define HW (224*224)

typedef __attribute__((ext_vector_type(8))) short s16x8;
typedef __attribute__((ext_vector_type(4))) float f32x4;
typedef __attribute__((ext_vector_type(4))) unsigned short u16x4;

__device__ __forceinline__ unsigned short f2bf(float f) {
    unsigned int u = __float_as_uint(f);
    u += 0x7fff + ((u >> 16) & 1);   // round-to-nearest-even
    return (unsigned short)(u >> 16);
}

__device__ __forceinline__ void load_lds16(const void* g, void* l) {
    __builtin_amdgcn_global_load_lds(
        (const __attribute__((address_space(1))) unsigned int*)g,
        (__attribute__((address_space(3))) unsigned int*)l, 16, 0, 0);
}

// ------- kernel 1: fused im2col(bf16) + patch entropy + weight cast ----------
// (R0's proven kernel, verbatim.)
// blocks [0,3136): one wave per patch -> bf16 A row + grayscale histogram.
// blocks [3136,3424): weight fp32->bf16 cast (384x768 row-major = B^T).
__global__ __launch_bounds__(256) void patch_kernel(const float* __restrict__ img,
                                                    const float* __restrict__ w,
                                                    unsigned short* __restrict__ A,
                                                    unsigned short* __restrict__ W,
                                                    float* __restrict__ ent) {
    if (blockIdx.x >= 3136) {                 // ---- weight cast part ----
        int t = (blockIdx.x - 3136) * 256 + threadIdx.x;   // 73728 float4s
        float4 v = ((const float4*)w)[t];
        u16x4 o = { f2bf(v.x), f2bf(v.y), f2bf(v.z), f2bf(v.w) };
        *(u16x4*)(W + t * 4) = o;
        return;
    }
    __shared__ int hist[4][32];
    const int lane = threadIdx.x & 63;
    const int wave = threadIdx.x >> 6;
    const int p = blockIdx.x * 4 + wave;      // 0..12543 == A row index
    const int b = p / NPATCH;
    const int n = p - b * NPATCH;
    const int ph = n / GW, pw = n - ph * GW;

    if (lane < 32) hist[wave][lane] = 0;
    __syncthreads();

    const int r = lane >> 2;                  // pixel row in patch 0..15
    const int cc = (lane & 3) * 4;            // pixel col 0,4,8,12
    const float* base = img + (size_t)b * (3 * HW) + (ph * 16 + r) * 224 + pw * 16 + cc;

    float4 v0 = *(const float4*)(base);
    float4 v1 = *(const float4*)(base + HW);
    float4 v2 = *(const float4*)(base + 2 * HW);

    unsigned short* arow = A + (size_t)p * KDIM;
    u16x4 o0 = { f2bf(v0.x), f2bf(v0.y), f2bf(v0.z), f2bf(v0.w) };
    u16x4 o1 = { f2bf(v1.x), f2bf(v1.y), f2bf(v1.z), f2bf(v1.w) };
    u16x4 o2 = { f2bf(v2.x), f2bf(v2.y), f2bf(v2.z), f2bf(v2.w) };
    *(u16x4*)(arow + 0 * 256 + lane * 4) = o0;
    *(u16x4*)(arow + 1 * 256 + lane * 4) = o1;
    *(u16x4*)(arow + 2 * 256 + lane * 4) = o2;

    float g[4] = { (v0.x + v1.x + v2.x) / 3.0f,
                   (v0.y + v1.y + v2.y) / 3.0f,
                   (v0.z + v1.z + v2.z) / 3.0f,
                   (v0.w + v1.w + v2.w) / 3.0f };
#pragma unroll
    for (int j = 0; j < 4; ++j) {
        int bin = (int)(g[j] * 31.0f);
        bin = bin < 0 ? 0 : (bin > 31 ? 31 : bin);
        atomicAdd(&hist[wave][bin], 1);
    }
    __syncthreads();

    float t = 0.0f;
    if (lane < 32) {
        float pr = (float)hist[wave][lane] * (1.0f / 256.0f);
        t = -pr * log2f(pr + 1e-10f);
    }
#pragma unroll
    for (int off = 32; off; off >>= 1) t += __shfl_xor(t, off);
    if (lane == 0) ent[p] = t * (1.0f / 5.0f);   // / log2(32)
}

// ------- kernel 2: pure bf16 MFMA GEMM, 32x128 tiles, XCD-swizzled ----------
// 1176 blocks (392 M-tiles x 3 N-tiles) x 256 threads (4 waves).
// XCD SWIZZLE (round 8): dispatch is round-robin (block d -> XCD d%8), so the
// 3 N-sibling blocks of one M-tile (consecutive ids) land on 3 DIFFERENT XCDs
// and each refetches the same A-panel from HBM (~3x A traffic). Remap
// (bijective, 1176 = 8*147): xcd = d&7 owns M-tiles [49*xcd, 49*xcd+49) with
// all 3 N-siblings local -> per-XCD A working set 2.4 MB fits the 4 MB L2,
// A is HBM-fetched exactly once.
// LDS: double-buffered [As 4KB | Bs 16KB] = 40KB -> 4 blocks/CU, 16 waves/CU.
// Staging via global_load_lds(16B), XOR swizzle pre-applied on global source
// (slot kss holds chunk kss^(row&7)); read slot sw=(ks*4+quad)^(cl&7).
// ONE barrier/K-tile. Writes raw x+bias; LayerNorm is a separate pass.
__global__ __launch_bounds__(256) void gemm_kernel(const unsigned short* __restrict__ A,
                                                   const unsigned short* __restrict__ Bt,
                                                   const float* __restrict__ bias,
                                                   float* __restrict__ C) {
    __shared__ __align__(16) unsigned short SH[2][1280 * 8];  // 40 KB

    const int tid  = threadIdx.x;
    const int lane = tid & 63;
    const int wv   = tid >> 6;                // wave 0..3
    const int quad = lane >> 4;
    const int cl   = lane & 15;
    const int bid  = blockIdx.x;              // 0..1175
    const int xcd  = bid & 7;                 // dispatch target XCD (round-robin)
    const int li   = bid >> 3;                // 0..146 local index on this XCD
    const int rowBase = (xcd * 49 + li / 3) * 32;
    const int colBase = (li % 3) * 128;

    // ---- staging constants: 5 chunks per thread (c = i*256 + tid) ----
    // c <  256 : As chunk -> row r=c>>3, slot kss=c&7, src col chunk kss^(r&7)
    // c >= 256 : Bs chunk -> row n=(c-256)>>3, same swizzle
    const unsigned short* srcs[5];
    {
#pragma unroll
        for (int i = 0; i < 5; ++i) {
            int c = i * 256 + tid;
            if (c < 256) {
                int r = c >> 3, kss = c & 7, ksg = kss ^ (r & 7);
                srcs[i] = A + (size_t)(rowBase + r) * KDIM + ksg * 8;
            } else {
                int cc = c - 256;
                int n = cc >> 3, kss = cc & 7, ksg = kss ^ (n & 7);
                srcs[i] = Bt + (size_t)(colBase + n) * KDIM + ksg * 8;
            }
        }
    }
    const int dstOff = tid * 8;               // shorts; chunk c at (c*8)

    // ---- prologue: stage tile 0 into buf 0 ----
#pragma unroll
    for (int i = 0; i < 5; ++i)
        load_lds16(srcs[i], &SH[0][i * 2048 + dstOff]);
    __syncthreads();

    f32x4 acc[2][2] = {};
#pragma unroll
    for (int kt = 0; kt < 12; ++kt) {
        const int cur = kt & 1;
        if (kt < 11) {                        // stage tile kt+1 into other buf
#pragma unroll
            for (int i = 0; i < 5; ++i)
                load_lds16(srcs[i] + (kt + 1) * 64, &SH[cur ^ 1][i * 2048 + dstOff]);
        }
        const unsigned short* As = SH[cur];
        const unsigned short* Bs = SH[cur] + 2048;
#pragma unroll
        for (int ks = 0; ks < 2; ++ks) {
            const int sw = (ks * 4 + quad) ^ (cl & 7);
            s16x8 af[2], bf[2];
#pragma unroll
            for (int i = 0; i < 2; ++i)
                af[i] = *(const s16x8*)(As + ((i * 16 + cl) * 8 + sw) * 8);
#pragma unroll
            for (int j = 0; j < 2; ++j)
                bf[j] = *(const s16x8*)(Bs + ((wv * 32 + j * 16 + cl) * 8 + sw) * 8);
#pragma unroll
            for (int i = 0; i < 2; ++i)
#pragma unroll
                for (int j = 0; j < 2; ++j)
                    acc[i][j] = __builtin_amdgcn_mfma_f32_16x16x32_bf16(
                        af[i], bf[j], acc[i][j], 0, 0, 0);
        }
        __syncthreads();                      // staging done + reads done
    }

    // ---- epilogue: + bias, write raw x (LN is a separate pass) ----
    float bv[2];
#pragma unroll
    for (int j = 0; j < 2; ++j)
        bv[j] = bias[colBase + wv * 32 + j * 16 + cl];
#pragma unroll
    for (int i = 0; i < 2; ++i)
#pragma unroll
        for (int r = 0; r < 4; ++r) {
            int row = rowBase + i * 16 + quad * 4 + r;
            float* crow = C + (size_t)row * DDIM + colBase + wv * 32;
#pragma unroll
            for (int j = 0; j < 2; ++j)
                crow[j * 16 + cl] = acc[i][j][r] + bv[j];
        }
}

// ------- kernel 3: in-place LayerNorm(384) over rows of out -----------------
// 3136 blocks x 256 threads; wave wv handles one row.
// XCD swizzle (3136 = 8*392, bijective): block on XCD x reads the C rows that
// gemm blocks on XCD x just wrote -> local-L2 hits instead of cross-die L3.
// Row = 192 float2; lane covers {lane, lane+64, lane+128} -> coalesced.
__global__ __launch_bounds__(256) void ln_kernel(float* __restrict__ x,
                                                 const float* __restrict__ gamma,
                                                 const float* __restrict__ beta) {
    const int lane = threadIdx.x & 63;
    const int wv   = threadIdx.x >> 6;
    const int d    = blockIdx.x;              // 0..3135
    const int xcd  = d & 7;
    const int j    = d >> 3;                  // 0..391
    const int row  = (xcd * 49 + (j >> 3)) * 32 + (j & 7) * 4 + wv;

    float2* px = (float2*)(x + (size_t)row * DDIM);
    float2 v[3];
    float s1 = 0.0f, s2 = 0.0f;
#pragma unroll
    for (int k = 0; k < 3; ++k) {
        v[k] = px[lane + k * 64];
        s1 += v[k].x + v[k].y;
        s2 += v[k].x * v[k].x + v[k].y * v[k].y;
    }
#pragma unroll
    for (int off = 1; off < 64; off <<= 1) {
        s1 += __shfl_xor(s1, off);
        s2 += __shfl_xor(s2, off);
    }
    float mu  = s1 * (1.0f / (float)DDIM);
    float var = s2 * (1.0f / (float)DDIM) - mu * mu;
    float rs  = rsqrtf(var + 1e-5f);
#pragma unroll
    for (int k = 0; k < 3; ++k) {
        int c2 = lane + k * 64;
        float2 g = ((const float2*)gamma)[c2];
        float2 b = ((const float2*)beta)[c2];
        float2 o;
        o.x = (v[k].x - mu) * rs * g.x + b.x;
        o.y = (v[k].y - mu) * rs * g.y + b.y;
        px[c2] = o;
    }
}

extern "C" void kernel_launch(void* const* d_in, const int* in_sizes, int n_in,
                              void* d_out, int out_size, void* d_ws, size_t ws_size,
                              hipStream_t stream) {
    const float* img = (const float*)d_in[0];
    const float* pw  = (const float*)d_in[1];
    const float* pb  = (const float*)d_in[2];
    const float* gam = (const float*)d_in[3];
    const float* bet = (const float*)d_in[4];
    float* out = (float*)d_out;

    unsigned short* Abf = (unsigned short*)d_ws;                       // 12544*768*2 = 19267584 B
    unsigned short* Wbf = (unsigned short*)((char*)d_ws + 19267584);   // 384*768*2  = 589824 B
    float* ent = out + (size_t)M_ROWS * DDIM;                          // entropy after x

    hipLaunchKernelGGL(patch_kernel, dim3(3424), dim3(256), 0, stream,
                       img, pw, Abf, Wbf, ent);
    hipLaunchKernelGGL(gemm_kernel,  dim3(1176), dim3(256), 0, stream,
                       Abf, Wbf, pb, out);
    hipLaunchKernelGGL(ln_kernel,    dim3(3136), dim3(256), 0, stream,
                       out, gam, bet);
}